// Round 3
// baseline (392.608 us; speedup 1.0000x reference)
//
#include <hip/hip_runtime.h>
#include <hip/hip_bf16.h>
#include <stdint.h>

#define BATCH 128
#define SEQ   512
#define NW    6
#define DIM   64
#define NELEM (BATCH * SEQ * NW)   // 393216
#define PI_F  3.14159265358979323846f

typedef float v2f __attribute__((ext_vector_type(2)));
typedef uint16_t u16x8 __attribute__((ext_vector_type(8)));

__device__ __forceinline__ v2f pkfma(float s, v2f m, v2f a) {
    return __builtin_elementwise_fma((v2f){s, s}, m, a);
}

// Interleaved 6-way DPP wave-64 reduction stage. After shr1,2,4,8 +
// bcast15,31 the totals land in lane 63.
template <int CTRL>
__device__ __forceinline__ void red_stage6(float v[6]) {
#pragma unroll
    for (int k = 0; k < 6; ++k)
        v[k] += __int_as_float(__builtin_amdgcn_update_dpp(
            0, __float_as_int(v[k]), CTRL, 0xF, 0xF, false));
}

// DPP move: v[lane] = v[src(lane)] per CTRL (all source lanes valid).
template <int CTRL>
__device__ __forceinline__ float dpp_mov(float x) {
    return __int_as_float(__builtin_amdgcn_update_dpp(
        0, __float_as_int(x), CTRL, 0xF, 0xF, false));
}

// Branch-free sincos(h/2), |h| <= 1. Trimmed to the bf16-output tolerance.
__device__ __forceinline__ void sincos_half(float h, float& s, float& c) {
    const float u = h * h;
    c = fmaf(u, fmaf(u, 2.6041667e-3f, -0.125f), 1.0f);
    s = h * fmaf(u, fmaf(u, 2.6041667e-4f, -2.0833333e-2f), 0.5f);
}

__device__ __forceinline__ float ldf(const void* p, int i, bool bf) {
    if (bf) {
        uint32_t u = (uint32_t)((const uint16_t*)p)[i];
        return __uint_as_float(u << 16);
    }
    return ((const float*)p)[i];
}

// ---------------------------------------------------------------------------
// Kernel 1 (msetup + misc):
//  - blocks [0,32): 4 waves/block evolve one (dir,col) basis column; writes
//    row-major Mg (cols 0-31 consumed as registers by k_sim) and the
//    pair-major transposed Mgt for cols 32-63 (consumed via LDS by k_sim)
//  - block 32: misc fills + flag post
// ---------------------------------------------------------------------------
__global__ void k_prep(const void* ang, const void* poly, const void* fp,
                       const void* bp, const void* fc, const void* bc,
                       float* __restrict__ misc, float* __restrict__ Mg,
                       float* __restrict__ Mgt, int* __restrict__ flag) {
    __shared__ int cnt;
    if (threadIdx.x == 0) cnt = 0;
    __syncthreads();
    {
        uint32_t w = ((const uint32_t*)ang)[threadIdx.x & 255];
        uint32_t e = (w >> 8) & 0xFFu;
        if (e >= 0x3Au && e <= 0x41u) atomicAdd(&cnt, 1);
    }
    __syncthreads();
    const bool bf = (cnt >= 128);

    if (blockIdx.x == 32) {
        if (threadIdx.x == 0)      misc[76] = ldf(fc, 0, bf);
        else if (threadIdx.x == 1) misc[77] = ldf(bc, 0, bf);
        else if (threadIdx.x == 2) *flag = bf ? 1 : 0;
        return;
    }

    // ---- msetup path: 4 columns per block (one per wave) ----
    const int lane = threadIdx.x & 63;
    const int tix  = blockIdx.x * 4 + (threadIdx.x >> 6);
    const int dir  = tix >> 6;
    const int col  = tix & 63;
    const void* prm = dir ? bp : fp;
    const int p = lane;

    float yr = (p == col) ? 1.f : 0.f;
    float yi = 0.f;

#pragma unroll
    for (int d = 0; d < 4; ++d) {
        const float th = 0.5f * PI_F * ldf(poly, d, bf) *
                         (float)(6 - 2 * (int)__popc((unsigned)p));
        float s, c;
        __sincosf(th, &s, &c);
        const float nr = yr * c + yi * s;
        const float ni = yi * c - yr * s;
        yr = nr; yi = ni;
#pragma unroll
        for (int k = 0; k < 6; ++k) {
            const int cw = k, tw = (k + 1) % 6;
            const int src = p ^ (((p >> (5 - cw)) & 1) << (5 - tw));
            yr = __shfl(yr, src, 64);
            yi = __shfl(yi, src, 64);
        }
    }

    int idx = 0;
#pragma unroll
    for (int l = 0; l < 2; ++l) {
#pragma unroll
        for (int w = 0; w < 6; ++w) {
            float cx, sx, cy, sy, cz, sz;
            __sincosf(0.5f * ldf(prm, idx + 0, bf), &sx, &cx);
            __sincosf(0.5f * ldf(prm, idx + 1, bf), &sy, &cy);
            __sincosf(0.5f * ldf(prm, idx + 2, bf), &sz, &cz);
            idx += 3;
            const float A = cy * cx, B = sy * sx, C = sy * cx, D = cy * sx;
            const float U00r = cz * A + sz * B, U00i = cz * B - sz * A;
            const float U11r = U00r,            U11i = sz * A - cz * B;
            const float Xr   = cz * C + sz * D, Xi   = sz * C - cz * D;
            const int m  = 1 << (5 - w);
            const int bb = (p >> (5 - w)) & 1;
            const float C1r = bb ? U11r : U00r;
            const float C1i = bb ? U11i : U00i;
            const float C2r = bb ? Xr : -Xr;
            const float C2i = Xi;
            const float pr = __shfl_xor(yr, m, 64);
            const float pi = __shfl_xor(yi, m, 64);
            const float nr = C1r * yr - C1i * yi + C2r * pr - C2i * pi;
            const float ni = C1r * yi + C1i * yr + C2r * pi + C2i * pr;
            yr = nr; yi = ni;
        }
#pragma unroll
        for (int k = 0; k < 5; ++k) {
            const int src = p ^ (((p >> (5 - k)) & 1) << (5 - (k + 1)));
            yr = __shfl(yr, src, 64);
            yi = __shfl(yi, src, 64);
        }
    }

    // row-major (cols 0-31 used as the k_sim register half)
    float* out = Mg + ((size_t)(dir * 64 + p) * 64 + (size_t)col) * 2;
    out[0] = yr;
    out[1] = yi;
    // pair-major transpose for cols 32-63 (k_sim LDS half)
    if (col >= 32) {
        const int pp = (col - 32) >> 1;
        float2* mt = (float2*)(Mgt +
            (((size_t)(dir * 16 + pp) * 64 + p) * 2 + (col & 1)) * 2);
        *mt = (float2){yr, yi};
    }
}

// ---------------------------------------------------------------------------
// Kernel 2: recurrent sim — ONE wave per chain, zero barriers in-loop.
//   * M columns 0-31 in VGPRs (64 regs); columns 32-63 in LDS pair-major
//     (mlds[pair][lane], contiguous-1KB conflict-free ds_read_b128, issued
//     at loop top -> latency hidden; caps arch-VGPR need ~190 so nothing
//     spills to AGPR/scratch, which was round-1's ~2x per-step cost).
//   * partners: xor32 permlane32_swap+select, xor16 permlane16_swap+select,
//     xor8 DPP row_ror:8, xor4 ds_swizzle (only DS partner op, issued first),
//     xor2/xor1 quad_perm.
//   * 6 interleaved DPP trees; z -> h via readlane(63).
// ---------------------------------------------------------------------------
__global__ void __launch_bounds__(64, 1) k_sim(const void* __restrict__ ang,
                                               const float* __restrict__ Mg,
                                               const float* __restrict__ Mgt,
                                               float* __restrict__ hbuf,
                                               const int* __restrict__ flag) {
    const int lane  = threadIdx.x;           // 0..63, one wave
    const int chain = blockIdx.x;            // 0..255
    const int dir   = chain >> 7;
    const int b     = chain & 127;
    const bool bf   = (*flag != 0);

    __shared__ __align__(16) float  cl[SEQ * 12];   // 24 KB cos/sin(x)
    __shared__ __align__(16) float  zb[SEQ * NW];   // 12 KB output buffer
    __shared__ float4 mlds[16 * 64];                // 16 KB M cols 32-63

    // ---- stage: convert this chain's 3072 angles -> cos/sin in LDS ----
    if (!bf) {
        const float4* src =
            (const float4*)((const float*)ang + (size_t)b * (SEQ * NW));
#pragma unroll
        for (int k = 0; k < 12; ++k) {
            const int v = k * 64 + lane;          // float4 index 0..767
            const float4 a = src[v];
            __align__(16) float o[8];
            float s, c;
            __sincosf(a.x, &s, &c); o[0] = c; o[1] = s;
            __sincosf(a.y, &s, &c); o[2] = c; o[3] = s;
            __sincosf(a.z, &s, &c); o[4] = c; o[5] = s;
            __sincosf(a.w, &s, &c); o[6] = c; o[7] = s;
            ((float4*)cl)[2 * v]     = ((const float4*)o)[0];
            ((float4*)cl)[2 * v + 1] = ((const float4*)o)[1];
        }
    } else {
        const u16x8* src =
            (const u16x8*)((const uint16_t*)ang + (size_t)b * (SEQ * NW));
#pragma unroll
        for (int k = 0; k < 6; ++k) {
            const int v = k * 64 + lane;          // u16x8 index 0..383
            const u16x8 a = src[v];
            __align__(16) float o[16];
#pragma unroll
            for (int e = 0; e < 8; ++e) {
                const float x = __uint_as_float(((uint32_t)a[e]) << 16);
                float s, c;
                __sincosf(x, &s, &c);
                o[2 * e] = c; o[2 * e + 1] = s;
            }
#pragma unroll
            for (int j = 0; j < 4; ++j)
                ((float4*)cl)[4 * v + j] = ((const float4*)o)[j];
        }
    }

    // ---- stage: M cols 32-63 into LDS (pair-major, conflict-free) ----
    {
        const float4* mgt4 = (const float4*)Mgt;
#pragma unroll
        for (int k = 0; k < 16; ++k)
            mlds[k * 64 + lane] = mgt4[(size_t)(dir * 16 + k) * 64 + lane];
    }

    // ---- M cols 0-31 for this lane's row: 32 complex = 64 VGPRs ----
    v2f Mreg[32];
    {
        const float4* mr4 =
            (const float4*)(Mg + (size_t)(dir * 64 + lane) * 128);
#pragma unroll
        for (int k = 0; k < 16; ++k) {
            const float4 m = mr4[k];
            Mreg[2 * k]     = (v2f){m.x, m.y};
            Mreg[2 * k + 1] = (v2f){m.z, m.w};
        }
    }

    // per-wire Z sign masks
    int zmask[6];
#pragma unroll
    for (int w = 0; w < 6; ++w) zmask[w] = ((lane >> (5 - w)) & 1) << 31;

    // walking pointers
    const float* cp = cl + (dir ? (SEQ - 1) * 12 : 0);
    const int   cstep = dir ? -12 : 12;
    float*       zp = zb + (dir ? (SEQ - 1) * NW : 0);
    const int   zstep = dir ? -NW : NW;

    float h[6] = {0.f, 0.f, 0.f, 0.f, 0.f, 0.f};

    __syncthreads();   // staging LDS writes visible before loop reads

    for (int t = 0; t < SEQ; ++t) {
        // LDS window first: M cols 32-63 + this step's cos/sin. No in-loop
        // dependency -> latency hides under e-build + register matvec.
        float4 mb[16];
#pragma unroll
        for (int k = 0; k < 16; ++k) mb[k] = mlds[k * 64 + lane];
        const float4 xq0 = ((const float4*)cp)[0];
        const float4 xq1 = ((const float4*)cp)[1];
        const float4 xq2 = ((const float4*)cp)[2];
        cp += cstep;

        // e(h) = eH (wires 0-2, col bits 5..3) ⊗ eL (wires 3-5, col bits 2..0)
        float cw[6], sw[6];
#pragma unroll
        for (int w = 0; w < 6; ++w) sincos_half(h[w], sw[w], cw[w]);
        float g01[4], g45[4], eH[8], eL[8];
        g01[0] = cw[0] * cw[1]; g01[1] = cw[0] * sw[1];
        g01[2] = sw[0] * cw[1]; g01[3] = sw[0] * sw[1];
        g45[0] = cw[4] * cw[5]; g45[1] = cw[4] * sw[5];
        g45[2] = sw[4] * cw[5]; g45[3] = sw[4] * sw[5];
#pragma unroll
        for (int j = 0; j < 8; ++j) {
            eH[j] = g01[j >> 1] * ((j & 1) ? sw[2] : cw[2]);
            eL[j] = ((j >> 2) ? sw[3] : cw[3]) * g45[j & 3];
        }

        // y[lane] = sum_c M[lane,c] * e[c]: register half then LDS half
        v2f y = {0.f, 0.f};
#pragma unroll
        for (int jh = 0; jh < 4; ++jh) {
            v2f n = {0.f, 0.f};
#pragma unroll
            for (int jl = 0; jl < 8; ++jl)
                n = pkfma(eL[jl], Mreg[8 * jh + jl], n);
            y = pkfma(eH[jh], n, y);
        }
#pragma unroll
        for (int g = 0; g < 4; ++g) {
            v2f n = {0.f, 0.f};
#pragma unroll
            for (int j2 = 0; j2 < 4; ++j2) {
                const float4 Q = mb[4 * g + j2];
                n = pkfma(eL[2 * j2],     (v2f){Q.x, Q.y}, n);
                n = pkfma(eL[2 * j2 + 1], (v2f){Q.z, Q.w}, n);
            }
            y = pkfma(eH[4 + g], n, y);
        }
        const float yr = y.x, yi = y.y;
        const int yri = __float_as_int(yr), yii = __float_as_int(yi);

        // partners y[lane ^ m]: only xor4 still uses the DS pipe (issue first)
        float pr[6], pi[6];
        pr[3] = __int_as_float(__builtin_amdgcn_ds_swizzle(yri, 0x101F)); // xor4
        pi[3] = __int_as_float(__builtin_amdgcn_ds_swizzle(yii, 0x101F));
        {   // xor32 via permlane32_swap: a'=[lo,lo], b'=[hi,hi] for a=b=y
            auto r0 = __builtin_amdgcn_permlane32_swap(yri, yri, false, false);
            auto r1 = __builtin_amdgcn_permlane32_swap(yii, yii, false, false);
            pr[0] = __int_as_float((int)((lane & 32) ? r0[0] : r0[1]));
            pi[0] = __int_as_float((int)((lane & 32) ? r1[0] : r1[1]));
        }
        {   // xor16 via permlane16_swap: rows 1,3 take a', rows 0,2 take b'
            auto r0 = __builtin_amdgcn_permlane16_swap(yri, yri, false, false);
            auto r1 = __builtin_amdgcn_permlane16_swap(yii, yii, false, false);
            pr[1] = __int_as_float((int)((lane & 16) ? r0[0] : r0[1]));
            pi[1] = __int_as_float((int)((lane & 16) ? r1[0] : r1[1]));
        }
        pr[2] = dpp_mov<0x128>(yr);   // row_ror:8 == xor8 within 16-row
        pi[2] = dpp_mov<0x128>(yi);
        pr[4] = dpp_mov<0x4E>(yr);    // quad_perm [2,3,0,1] == xor2
        pi[4] = dpp_mov<0x4E>(yi);
        pr[5] = dpp_mov<0xB1>(yr);    // quad_perm [1,0,3,2] == xor1
        pi[5] = dpp_mov<0xB1>(yi);

        const float q = fmaf(yr, yr, yi * yi);
        const float cx[6] = {xq0.x, xq0.z, xq1.x, xq1.z, xq2.x, xq2.z};
        const float sx[6] = {xq0.y, xq0.w, xq1.y, xq1.w, xq2.y, xq2.w};

        // per-lane contribution to z_w = cx*Z_w - sx*X_w (linear in the sum)
        float v[6];
#pragma unroll
        for (int w = 0; w < 6; ++w) {
            const float cq  = __int_as_float(__float_as_int(cx[w] * q) ^ zmask[w]);
            const float dot = fmaf(yr, pr[w], yi * pi[w]);
            v[w] = fmaf(-sx[w], dot, cq);
        }

        red_stage6<0x111>(v);   // row_shr:1
        red_stage6<0x112>(v);   // row_shr:2
        red_stage6<0x114>(v);   // row_shr:4
        red_stage6<0x118>(v);   // row_shr:8
        red_stage6<0x142>(v);   // row_bcast:15
        red_stage6<0x143>(v);   // row_bcast:31

        if (lane == 63) {                       // lane 63 holds the totals
#pragma unroll
            for (int w = 0; w < 6; ++w) zp[w] = v[w];
        }
        zp += zstep;
#pragma unroll
        for (int w = 0; w < 6; ++w)
            h[w] = __int_as_float(
                __builtin_amdgcn_readlane(__float_as_int(v[w]), 63));
    }

    __syncthreads();   // orders lane-63 zb writes before the bulk read

    // ---- bulk store outputs: 768 float4 over 64 lanes ----
    {
        float* orow = hbuf + (size_t)dir * NELEM + (size_t)b * (SEQ * NW);
        const float4* zs4 = (const float4*)zb;
        float4* go = (float4*)orow;
#pragma unroll
        for (int k = 0; k < 12; ++k) {
            const int idx = k * 64 + lane;
            go[idx] = zs4[idx];
        }
    }
}

// ---------------------------------------------------------------------------
// Kernel 3: out = sigmoid(fc)*h_fwd + sigmoid(bc)*h_bwd, dtype per flag.
// ---------------------------------------------------------------------------
__global__ void k_combine(const float* __restrict__ hbuf,
                          const float* __restrict__ misc,
                          void* __restrict__ out, const int* __restrict__ flag) {
    const int i = blockIdx.x * blockDim.x + threadIdx.x;
    if (i >= NELEM) return;
    const float sf = 1.f / (1.f + __expf(-misc[76]));
    const float sb = 1.f / (1.f + __expf(-misc[77]));
    const float v = sf * hbuf[i] + sb * hbuf[NELEM + i];
    if (*flag) ((__hip_bfloat16*)out)[i] = __float2bfloat16(v);
    else       ((float*)out)[i] = v;
}

// ---------------------------------------------------------------------------
extern "C" void kernel_launch(void* const* d_in, const int* in_sizes, int n_in,
                              void* d_out, int out_size, void* d_ws, size_t ws_size,
                              hipStream_t stream) {
    const void* ang  = d_in[0];
    const void* poly = d_in[1];
    const void* fp   = d_in[2];
    const void* bp   = d_in[3];
    const void* fc   = d_in[4];
    const void* bc   = d_in[5];

    // ws (floats): pad[32] | misc[128] | hbuf[2*NELEM] | Mg[16384] |
    //              Mgt[8192] | flag
    float* misc = (float*)d_ws + 32;
    float* hbuf = misc + 128;
    float* Mg   = hbuf + 2 * NELEM;
    float* Mgt  = Mg + 2 * 64 * 64 * 2;
    int*   flag = (int*)(Mgt + 2 * 16 * 64 * 4);

    k_prep<<<33, 256, 0, stream>>>(ang, poly, fp, bp, fc, bc,
                                   misc, Mg, Mgt, flag);
    k_sim<<<256, 64, 0, stream>>>(ang, Mg, Mgt, hbuf, flag);
    k_combine<<<(NELEM + 255) / 256, 256, 0, stream>>>(hbuf, misc, d_out, flag);
}

// Round 4
// 385.028 us; speedup vs baseline: 1.0197x; 1.0197x over previous
//
#include <hip/hip_runtime.h>
#include <hip/hip_bf16.h>
#include <stdint.h>

#define BATCH 128
#define SEQ   512
#define NW    6
#define DIM   64
#define NELEM (BATCH * SEQ * NW)   // 393216
#define PI_F  3.14159265358979323846f

typedef float v2f __attribute__((ext_vector_type(2)));
typedef uint16_t u16x8 __attribute__((ext_vector_type(8)));

__device__ __forceinline__ v2f pkfma(float s, v2f m, v2f a) {
    return __builtin_elementwise_fma((v2f){s, s}, m, a);
}

// Interleaved 6-way DPP wave-64 reduction stage. After shr1,2,4,8 +
// bcast15,31 the totals land in lane 63.
template <int CTRL>
__device__ __forceinline__ void red_stage6(float v[6]) {
#pragma unroll
    for (int k = 0; k < 6; ++k)
        v[k] += __int_as_float(__builtin_amdgcn_update_dpp(
            0, __float_as_int(v[k]), CTRL, 0xF, 0xF, false));
}

// DPP move: v[lane] = v[src(lane)] per CTRL (all source lanes valid).
template <int CTRL>
__device__ __forceinline__ float dpp_mov(float x) {
    return __int_as_float(__builtin_amdgcn_update_dpp(
        0, __float_as_int(x), CTRL, 0xF, 0xF, false));
}

// Branch-free sincos(h/2), |h| <= 1. Trimmed to the bf16-output tolerance.
__device__ __forceinline__ void sincos_half(float h, float& s, float& c) {
    const float u = h * h;
    c = fmaf(u, fmaf(u, 2.6041667e-3f, -0.125f), 1.0f);
    s = h * fmaf(u, fmaf(u, 2.6041667e-4f, -2.0833333e-2f), 0.5f);
}

__device__ __forceinline__ float ldf(const void* p, int i, bool bf) {
    if (bf) {
        uint32_t u = (uint32_t)((const uint16_t*)p)[i];
        return __uint_as_float(u << 16);
    }
    return ((const float*)p)[i];
}

// ---------------------------------------------------------------------------
// Kernel 1 (msetup + misc):
//  - blocks [0,32): 4 waves/block evolve one (dir,col) basis column -> Mg
//  - block 32: misc fills + flag post
// ---------------------------------------------------------------------------
__global__ void k_prep(const void* ang, const void* poly, const void* fp,
                       const void* bp, const void* fc, const void* bc,
                       float* __restrict__ misc, float* __restrict__ Mg,
                       int* __restrict__ flag) {
    __shared__ int cnt;
    if (threadIdx.x == 0) cnt = 0;
    __syncthreads();
    {
        uint32_t w = ((const uint32_t*)ang)[threadIdx.x & 255];
        uint32_t e = (w >> 8) & 0xFFu;
        if (e >= 0x3Au && e <= 0x41u) atomicAdd(&cnt, 1);
    }
    __syncthreads();
    const bool bf = (cnt >= 128);

    if (blockIdx.x == 32) {
        if (threadIdx.x == 0)      misc[76] = ldf(fc, 0, bf);
        else if (threadIdx.x == 1) misc[77] = ldf(bc, 0, bf);
        else if (threadIdx.x == 2) *flag = bf ? 1 : 0;
        return;
    }

    // ---- msetup path: 4 columns per block (one per wave) ----
    const int lane = threadIdx.x & 63;
    const int tix  = blockIdx.x * 4 + (threadIdx.x >> 6);
    const int dir  = tix >> 6;
    const int col  = tix & 63;
    const void* prm = dir ? bp : fp;
    const int p = lane;

    float yr = (p == col) ? 1.f : 0.f;
    float yi = 0.f;

#pragma unroll
    for (int d = 0; d < 4; ++d) {
        const float th = 0.5f * PI_F * ldf(poly, d, bf) *
                         (float)(6 - 2 * (int)__popc((unsigned)p));
        float s, c;
        __sincosf(th, &s, &c);
        const float nr = yr * c + yi * s;
        const float ni = yi * c - yr * s;
        yr = nr; yi = ni;
#pragma unroll
        for (int k = 0; k < 6; ++k) {
            const int cw = k, tw = (k + 1) % 6;
            const int src = p ^ (((p >> (5 - cw)) & 1) << (5 - tw));
            yr = __shfl(yr, src, 64);
            yi = __shfl(yi, src, 64);
        }
    }

    int idx = 0;
#pragma unroll
    for (int l = 0; l < 2; ++l) {
#pragma unroll
        for (int w = 0; w < 6; ++w) {
            float cx, sx, cy, sy, cz, sz;
            __sincosf(0.5f * ldf(prm, idx + 0, bf), &sx, &cx);
            __sincosf(0.5f * ldf(prm, idx + 1, bf), &sy, &cy);
            __sincosf(0.5f * ldf(prm, idx + 2, bf), &sz, &cz);
            idx += 3;
            const float A = cy * cx, B = sy * sx, C = sy * cx, D = cy * sx;
            const float U00r = cz * A + sz * B, U00i = cz * B - sz * A;
            const float U11r = U00r,            U11i = sz * A - cz * B;
            const float Xr   = cz * C + sz * D, Xi   = sz * C - cz * D;
            const int m  = 1 << (5 - w);
            const int bb = (p >> (5 - w)) & 1;
            const float C1r = bb ? U11r : U00r;
            const float C1i = bb ? U11i : U00i;
            const float C2r = bb ? Xr : -Xr;
            const float C2i = Xi;
            const float pr = __shfl_xor(yr, m, 64);
            const float pi = __shfl_xor(yi, m, 64);
            const float nr = C1r * yr - C1i * yi + C2r * pr - C2i * pi;
            const float ni = C1r * yi + C1i * yr + C2r * pi + C2i * pr;
            yr = nr; yi = ni;
        }
#pragma unroll
        for (int k = 0; k < 5; ++k) {
            const int src = p ^ (((p >> (5 - k)) & 1) << (5 - (k + 1)));
            yr = __shfl(yr, src, 64);
            yi = __shfl(yi, src, 64);
        }
    }

    float* out = Mg + ((size_t)(dir * 64 + p) * 64 + (size_t)col) * 2;
    out[0] = yr;
    out[1] = yi;
}

// ---------------------------------------------------------------------------
// Kernel 2: recurrent sim — ONE wave per chain, zero barriers in-loop.
//   * amdgpu_waves_per_eu(1,1) pins the VGPR budget at 512: rounds 1/3
//     allocated exactly 132 (= the 4-waves/EU target) and AGPR-spilled the
//     M rows -> ~2x VALU issue per step. With the budget pinned, the FULL
//     M row lives in VGPRs (Mc[64] = 128 regs): no per-step M memory ops.
//   * all partner exchanges are VALU: xor32/xor16 permlane_swap+select
//     (selection harness-verified in round 3), xor8 row_ror:8, xor4 via
//     quad_perm[3,2,1,0] o row_half_mirror ((i^3)^7 = i^4), xor2/1
//     quad_perm. The DS pipe carries only prefetchable xq reads + zb
//     writes -> off the loop-carried chain.
//   * 6 interleaved DPP trees; z -> h via readlane(63).
// ---------------------------------------------------------------------------
__global__ void
__attribute__((amdgpu_flat_work_group_size(64, 64)))
__attribute__((amdgpu_waves_per_eu(1, 1)))
k_sim(const void* __restrict__ ang, const float* __restrict__ Mg,
      float* __restrict__ hbuf, const int* __restrict__ flag) {
    const int lane  = threadIdx.x;           // 0..63, one wave
    const int chain = blockIdx.x;            // 0..255
    const int dir   = chain >> 7;
    const int b     = chain & 127;
    const bool bf   = (*flag != 0);

    __shared__ __align__(16) float cl[SEQ * 12];   // 24 KB cos/sin(x)
    __shared__ __align__(16) float zb[SEQ * NW];   // 12 KB output buffer

    // ---- stage: convert this chain's 3072 angles -> cos/sin in LDS ----
    if (!bf) {
        const float4* src =
            (const float4*)((const float*)ang + (size_t)b * (SEQ * NW));
#pragma unroll
        for (int k = 0; k < 12; ++k) {
            const int v = k * 64 + lane;          // float4 index 0..767
            const float4 a = src[v];
            __align__(16) float o[8];
            float s, c;
            __sincosf(a.x, &s, &c); o[0] = c; o[1] = s;
            __sincosf(a.y, &s, &c); o[2] = c; o[3] = s;
            __sincosf(a.z, &s, &c); o[4] = c; o[5] = s;
            __sincosf(a.w, &s, &c); o[6] = c; o[7] = s;
            ((float4*)cl)[2 * v]     = ((const float4*)o)[0];
            ((float4*)cl)[2 * v + 1] = ((const float4*)o)[1];
        }
    } else {
        const u16x8* src =
            (const u16x8*)((const uint16_t*)ang + (size_t)b * (SEQ * NW));
#pragma unroll
        for (int k = 0; k < 6; ++k) {
            const int v = k * 64 + lane;          // u16x8 index 0..383
            const u16x8 a = src[v];
            __align__(16) float o[16];
#pragma unroll
            for (int e = 0; e < 8; ++e) {
                const float x = __uint_as_float(((uint32_t)a[e]) << 16);
                float s, c;
                __sincosf(x, &s, &c);
                o[2 * e] = c; o[2 * e + 1] = s;
            }
#pragma unroll
            for (int j = 0; j < 4; ++j)
                ((float4*)cl)[4 * v + j] = ((const float4*)o)[j];
        }
    }

    // ---- full M row for this lane: 64 complex cols = 128 VGPRs ----
    v2f Mc[64];
    {
        const float4* mr4 =
            (const float4*)(Mg + (size_t)(dir * 64 + lane) * 128);
#pragma unroll
        for (int k = 0; k < 32; ++k) {
            const float4 m = mr4[k];
            Mc[2 * k]     = (v2f){m.x, m.y};
            Mc[2 * k + 1] = (v2f){m.z, m.w};
        }
    }

    // per-wire Z sign masks
    int zmask[6];
#pragma unroll
    for (int w = 0; w < 6; ++w) zmask[w] = ((lane >> (5 - w)) & 1) << 31;

    // walking pointers
    const float* cp = cl + (dir ? (SEQ - 1) * 12 : 0);
    const int   cstep = dir ? -12 : 12;
    float*       zp = zb + (dir ? (SEQ - 1) * NW : 0);
    const int   zstep = dir ? -NW : NW;

    float h[6] = {0.f, 0.f, 0.f, 0.f, 0.f, 0.f};

    __syncthreads();   // staging LDS writes visible before loop reads

    for (int t = 0; t < SEQ; ++t) {
        // this step's cos/sin — issued first, latency hides under e-build
        const float4 xq0 = ((const float4*)cp)[0];
        const float4 xq1 = ((const float4*)cp)[1];
        const float4 xq2 = ((const float4*)cp)[2];
        cp += cstep;

        // e(h) = eH (wires 0-2, col bits 5..3) ⊗ eL (wires 3-5, col bits 2..0)
        float cw[6], sw[6];
#pragma unroll
        for (int w = 0; w < 6; ++w) sincos_half(h[w], sw[w], cw[w]);
        float g01[4], g45[4], eH[8], eL[8];
        g01[0] = cw[0] * cw[1]; g01[1] = cw[0] * sw[1];
        g01[2] = sw[0] * cw[1]; g01[3] = sw[0] * sw[1];
        g45[0] = cw[4] * cw[5]; g45[1] = cw[4] * sw[5];
        g45[2] = sw[4] * cw[5]; g45[3] = sw[4] * sw[5];
#pragma unroll
        for (int j = 0; j < 8; ++j) {
            eH[j] = g01[j >> 1] * ((j & 1) ? sw[2] : cw[2]);
            eL[j] = ((j >> 2) ? sw[3] : cw[3]) * g45[j & 3];
        }

        // y[lane] = sum_c M[lane,c] * e[c]  (two-stage contraction, 72 pkfma)
        v2f y = {0.f, 0.f};
#pragma unroll
        for (int jh = 0; jh < 8; ++jh) {
            v2f n = {0.f, 0.f};
#pragma unroll
            for (int jl = 0; jl < 8; ++jl)
                n = pkfma(eL[jl], Mc[8 * jh + jl], n);
            y = pkfma(eH[jh], n, y);
        }
        const float yr = y.x, yi = y.y;
        const int yri = __float_as_int(yr), yii = __float_as_int(yi);

        // partners y[lane ^ m]: all VALU/DPP, nothing on the DS pipe
        float pr[6], pi[6];
        {   // xor32 via permlane32_swap (+select verified in round 3)
            auto r0 = __builtin_amdgcn_permlane32_swap(yri, yri, false, false);
            auto r1 = __builtin_amdgcn_permlane32_swap(yii, yii, false, false);
            pr[0] = __int_as_float((int)((lane & 32) ? r0[0] : r0[1]));
            pi[0] = __int_as_float((int)((lane & 32) ? r1[0] : r1[1]));
        }
        {   // xor16 via permlane16_swap (+select verified in round 3)
            auto r0 = __builtin_amdgcn_permlane16_swap(yri, yri, false, false);
            auto r1 = __builtin_amdgcn_permlane16_swap(yii, yii, false, false);
            pr[1] = __int_as_float((int)((lane & 16) ? r0[0] : r0[1]));
            pi[1] = __int_as_float((int)((lane & 16) ? r1[0] : r1[1]));
        }
        pr[2] = dpp_mov<0x128>(yr);   // row_ror:8 == xor8 within 16-row
        pi[2] = dpp_mov<0x128>(yi);
        pr[3] = dpp_mov<0x141>(dpp_mov<0x1B>(yr));  // (i^3)^7 = i^4
        pi[3] = dpp_mov<0x141>(dpp_mov<0x1B>(yi));
        pr[4] = dpp_mov<0x4E>(yr);    // quad_perm [2,3,0,1] == xor2
        pi[4] = dpp_mov<0x4E>(yi);
        pr[5] = dpp_mov<0xB1>(yr);    // quad_perm [1,0,3,2] == xor1
        pi[5] = dpp_mov<0xB1>(yi);

        const float q = fmaf(yr, yr, yi * yi);
        const float cx[6] = {xq0.x, xq0.z, xq1.x, xq1.z, xq2.x, xq2.z};
        const float sx[6] = {xq0.y, xq0.w, xq1.y, xq1.w, xq2.y, xq2.w};

        // per-lane contribution to z_w = cx*Z_w - sx*X_w (linear in the sum)
        float v[6];
#pragma unroll
        for (int w = 0; w < 6; ++w) {
            const float cq  = __int_as_float(__float_as_int(cx[w] * q) ^ zmask[w]);
            const float dot = fmaf(yr, pr[w], yi * pi[w]);
            v[w] = fmaf(-sx[w], dot, cq);
        }

        red_stage6<0x111>(v);   // row_shr:1
        red_stage6<0x112>(v);   // row_shr:2
        red_stage6<0x114>(v);   // row_shr:4
        red_stage6<0x118>(v);   // row_shr:8
        red_stage6<0x142>(v);   // row_bcast:15
        red_stage6<0x143>(v);   // row_bcast:31

        if (lane == 63) {                       // lane 63 holds the totals
#pragma unroll
            for (int w = 0; w < 6; ++w) zp[w] = v[w];
        }
        zp += zstep;
#pragma unroll
        for (int w = 0; w < 6; ++w)
            h[w] = __int_as_float(
                __builtin_amdgcn_readlane(__float_as_int(v[w]), 63));
    }

    __syncthreads();   // orders lane-63 zb writes before the bulk read

    // ---- bulk store outputs: 768 float4 over 64 lanes ----
    {
        float* orow = hbuf + (size_t)dir * NELEM + (size_t)b * (SEQ * NW);
        const float4* zs4 = (const float4*)zb;
        float4* go = (float4*)orow;
#pragma unroll
        for (int k = 0; k < 12; ++k) {
            const int idx = k * 64 + lane;
            go[idx] = zs4[idx];
        }
    }
}

// ---------------------------------------------------------------------------
// Kernel 3: out = sigmoid(fc)*h_fwd + sigmoid(bc)*h_bwd, dtype per flag.
// ---------------------------------------------------------------------------
__global__ void k_combine(const float* __restrict__ hbuf,
                          const float* __restrict__ misc,
                          void* __restrict__ out, const int* __restrict__ flag) {
    const int i = blockIdx.x * blockDim.x + threadIdx.x;
    if (i >= NELEM) return;
    const float sf = 1.f / (1.f + __expf(-misc[76]));
    const float sb = 1.f / (1.f + __expf(-misc[77]));
    const float v = sf * hbuf[i] + sb * hbuf[NELEM + i];
    if (*flag) ((__hip_bfloat16*)out)[i] = __float2bfloat16(v);
    else       ((float*)out)[i] = v;
}

// ---------------------------------------------------------------------------
extern "C" void kernel_launch(void* const* d_in, const int* in_sizes, int n_in,
                              void* d_out, int out_size, void* d_ws, size_t ws_size,
                              hipStream_t stream) {
    const void* ang  = d_in[0];
    const void* poly = d_in[1];
    const void* fp   = d_in[2];
    const void* bp   = d_in[3];
    const void* fc   = d_in[4];
    const void* bc   = d_in[5];

    // ws (floats): pad[32] | misc[128] | hbuf[2*NELEM] | Mg[16384] | flag
    float* misc = (float*)d_ws + 32;
    float* hbuf = misc + 128;
    float* Mg   = hbuf + 2 * NELEM;
    int*   flag = (int*)(Mg + 2 * 64 * 64 * 2);

    k_prep<<<33, 256, 0, stream>>>(ang, poly, fp, bp, fc, bc, misc, Mg, flag);
    k_sim<<<256, 64, 0, stream>>>(ang, Mg, hbuf, flag);
    k_combine<<<(NELEM + 255) / 256, 256, 0, stream>>>(hbuf, misc, d_out, flag);
}

// Round 5
// 381.430 us; speedup vs baseline: 1.0293x; 1.0094x over previous
//
#include <hip/hip_runtime.h>
#include <hip/hip_bf16.h>
#include <stdint.h>

#define BATCH 128
#define SEQ   512
#define NW    6
#define DIM   64
#define NELEM (BATCH * SEQ * NW)   // 393216
#define PI_F  3.14159265358979323846f

typedef float v2f __attribute__((ext_vector_type(2)));
typedef uint16_t u16x8 __attribute__((ext_vector_type(8)));

__device__ __forceinline__ v2f pkfma(float s, v2f m, v2f a) {
    return __builtin_elementwise_fma((v2f){s, s}, m, a);
}

// Interleaved 6-way DPP wave-64 reduction stage. After shr1,2,4,8 +
// bcast15,31 the totals land in lane 63. (Harness-verified r1/r3/r4.)
template <int CTRL>
__device__ __forceinline__ void red_stage6(float v[6]) {
#pragma unroll
    for (int k = 0; k < 6; ++k)
        v[k] += __int_as_float(__builtin_amdgcn_update_dpp(
            0, __float_as_int(v[k]), CTRL, 0xF, 0xF, false));
}

// DPP move: v[lane] = v[src(lane)] per CTRL (all source lanes valid).
template <int CTRL>
__device__ __forceinline__ float dpp_mov(float x) {
    return __int_as_float(__builtin_amdgcn_update_dpp(
        0, __float_as_int(x), CTRL, 0xF, 0xF, false));
}

// Branch-free sincos(h/2), |h| <= 1. Trimmed to the bf16-output tolerance.
__device__ __forceinline__ void sincos_half(float h, float& s, float& c) {
    const float u = h * h;
    c = fmaf(u, fmaf(u, 2.6041667e-3f, -0.125f), 1.0f);
    s = h * fmaf(u, fmaf(u, 2.6041667e-4f, -2.0833333e-2f), 0.5f);
}

__device__ __forceinline__ float ldf(const void* p, int i, bool bf) {
    if (bf) {
        uint32_t u = (uint32_t)((const uint16_t*)p)[i];
        return __uint_as_float(u << 16);
    }
    return ((const float*)p)[i];
}

// ---------------------------------------------------------------------------
// Kernel 1 (msetup + misc):
//  - blocks [0,32): 4 waves/block evolve one (dir,col) basis column -> Mg
//  - block 32: misc fills + flag post
// ---------------------------------------------------------------------------
__global__ void k_prep(const void* ang, const void* poly, const void* fp,
                       const void* bp, const void* fc, const void* bc,
                       float* __restrict__ misc, float* __restrict__ Mg,
                       int* __restrict__ flag) {
    __shared__ int cnt;
    if (threadIdx.x == 0) cnt = 0;
    __syncthreads();
    {
        uint32_t w = ((const uint32_t*)ang)[threadIdx.x & 255];
        uint32_t e = (w >> 8) & 0xFFu;
        if (e >= 0x3Au && e <= 0x41u) atomicAdd(&cnt, 1);
    }
    __syncthreads();
    const bool bf = (cnt >= 128);

    if (blockIdx.x == 32) {
        if (threadIdx.x == 0)      misc[76] = ldf(fc, 0, bf);
        else if (threadIdx.x == 1) misc[77] = ldf(bc, 0, bf);
        else if (threadIdx.x == 2) *flag = bf ? 1 : 0;
        return;
    }

    // ---- msetup path: 4 columns per block (one per wave) ----
    const int lane = threadIdx.x & 63;
    const int tix  = blockIdx.x * 4 + (threadIdx.x >> 6);
    const int dir  = tix >> 6;
    const int col  = tix & 63;
    const void* prm = dir ? bp : fp;
    const int p = lane;

    float yr = (p == col) ? 1.f : 0.f;
    float yi = 0.f;

#pragma unroll
    for (int d = 0; d < 4; ++d) {
        const float th = 0.5f * PI_F * ldf(poly, d, bf) *
                         (float)(6 - 2 * (int)__popc((unsigned)p));
        float s, c;
        __sincosf(th, &s, &c);
        const float nr = yr * c + yi * s;
        const float ni = yi * c - yr * s;
        yr = nr; yi = ni;
#pragma unroll
        for (int k = 0; k < 6; ++k) {
            const int cw = k, tw = (k + 1) % 6;
            const int src = p ^ (((p >> (5 - cw)) & 1) << (5 - tw));
            yr = __shfl(yr, src, 64);
            yi = __shfl(yi, src, 64);
        }
    }

    int idx = 0;
#pragma unroll
    for (int l = 0; l < 2; ++l) {
#pragma unroll
        for (int w = 0; w < 6; ++w) {
            float cx, sx, cy, sy, cz, sz;
            __sincosf(0.5f * ldf(prm, idx + 0, bf), &sx, &cx);
            __sincosf(0.5f * ldf(prm, idx + 1, bf), &sy, &cy);
            __sincosf(0.5f * ldf(prm, idx + 2, bf), &sz, &cz);
            idx += 3;
            const float A = cy * cx, B = sy * sx, C = sy * cx, D = cy * sx;
            const float U00r = cz * A + sz * B, U00i = cz * B - sz * A;
            const float U11r = U00r,            U11i = sz * A - cz * B;
            const float Xr   = cz * C + sz * D, Xi   = sz * C - cz * D;
            const int m  = 1 << (5 - w);
            const int bb = (p >> (5 - w)) & 1;
            const float C1r = bb ? U11r : U00r;
            const float C1i = bb ? U11i : U00i;
            const float C2r = bb ? Xr : -Xr;
            const float C2i = Xi;
            const float pr = __shfl_xor(yr, m, 64);
            const float pi = __shfl_xor(yi, m, 64);
            const float nr = C1r * yr - C1i * yi + C2r * pr - C2i * pi;
            const float ni = C1r * yi + C1i * yr + C2r * pi + C2i * pr;
            yr = nr; yi = ni;
        }
#pragma unroll
        for (int k = 0; k < 5; ++k) {
            const int src = p ^ (((p >> (5 - k)) & 1) << (5 - (k + 1)));
            yr = __shfl(yr, src, 64);
            yi = __shfl(yi, src, 64);
        }
    }

    float* out = Mg + ((size_t)(dir * 64 + p) * 64 + (size_t)col) * 2;
    out[0] = yr;
    out[1] = yi;
}

// ---------------------------------------------------------------------------
// Kernel 2: recurrent sim — 4 waves/chain (the register layout the allocator
// provably keeps in arch VGPRs: round-0 measured VGPR_Count=68, no spills),
// but with ONE barrier per step instead of round-0's two:
//   * each wave: 16-col matvec partial (20 pkfma) -> pY[buf][wv][lane],
//     __syncthreads(), then every wave reassembles full y (3 ds_read_b64)
//     and does the ENTIRE measurement wave-locally & redundantly (runs on 4
//     separate SIMDs -> free): all-VALU partner exchanges (permlane32/16
//     swap, row_ror:8, (i^3)^7=i^4, quad_perms — harness-verified r3/r4) +
//     6-way DPP tree with cx/sx folded in. No mR slab, no bpermute window,
//     no second barrier.
//   * xq cos/sin for step t+1 read BEFORE the barrier (off the post-barrier
//     critical path).
// ---------------------------------------------------------------------------
__global__ void __launch_bounds__(256, 1) k_sim(const void* __restrict__ ang,
                                                const float* __restrict__ Mg,
                                                float* __restrict__ hbuf,
                                                const int* __restrict__ flag) {
    const int tid   = threadIdx.x;
    const int lane  = tid & 63;
    const int wv    = tid >> 6;              // wave 0..3
    const int chain = blockIdx.x;            // 0..255
    const int dir   = chain >> 7;
    const int b     = chain & 127;
    const bool bf   = (*flag != 0);

    __shared__ __align__(16) float  cl[SEQ * 12];   // 24 KB cos/sin(x)
    __shared__ __align__(16) float  zb[SEQ * NW];   // 12 KB output buffer
    __shared__ float2 pY[2][4][DIM];                // ping-pong partials, 4 KB

    // ---- stage: convert this chain's 3072 angles -> cos/sin in LDS ----
    if (!bf) {
        const float4* src =
            (const float4*)((const float*)ang + (size_t)b * (SEQ * NW));
#pragma unroll
        for (int k = 0; k < 3; ++k) {
            const int v = k * 256 + tid;          // float4 index 0..767
            const float4 a = src[v];
            __align__(16) float o[8];
            float s, c;
            __sincosf(a.x, &s, &c); o[0] = c; o[1] = s;
            __sincosf(a.y, &s, &c); o[2] = c; o[3] = s;
            __sincosf(a.z, &s, &c); o[4] = c; o[5] = s;
            __sincosf(a.w, &s, &c); o[6] = c; o[7] = s;
            ((float4*)cl)[2 * v]     = ((const float4*)o)[0];
            ((float4*)cl)[2 * v + 1] = ((const float4*)o)[1];
        }
    } else {
        const u16x8* src =
            (const u16x8*)((const uint16_t*)ang + (size_t)b * (SEQ * NW));
#pragma unroll
        for (int k = 0; k < 2; ++k) {
            const int v = k * 256 + tid;          // u16x8 index 0..383
            if (v < 384) {
                const u16x8 a = src[v];
                __align__(16) float o[16];
#pragma unroll
                for (int e = 0; e < 8; ++e) {
                    const float x = __uint_as_float(((uint32_t)a[e]) << 16);
                    float s, c;
                    __sincosf(x, &s, &c);
                    o[2 * e] = c; o[2 * e + 1] = s;
                }
#pragma unroll
                for (int j = 0; j < 4; ++j)
                    ((float4*)cl)[4 * v + j] = ((const float4*)o)[j];
            }
        }
    }

    // ---- my 16 resident M columns: row = lane, cols = 16wv..16wv+15 ----
    v2f Mres[16];
    {
        const float2* mr2 =
            (const float2*)(Mg + (size_t)(dir * 64 + lane) * 128 + 32 * wv);
#pragma unroll
        for (int k = 0; k < 16; ++k) Mres[k] = (v2f){mr2[k].x, mr2[k].y};
    }

    // per-wire Z sign masks
    int zmask[6];
#pragma unroll
    for (int w = 0; w < 6; ++w) zmask[w] = ((lane >> (5 - w)) & 1) << 31;
    const int ow0 = wv ^ 1, ow1 = wv ^ 2, ow2 = wv ^ 3;   // other waves

    float h[6] = {0.f, 0.f, 0.f, 0.f, 0.f, 0.f};

    // encode h -> my 16-col matvec partial (round-0 verbatim, verified)
    auto encode_matvec = [&](v2f& acc) {
        float cw6[6], sw6[6];
#pragma unroll
        for (int w = 0; w < 6; ++w) sincos_half(h[w], sw6[w], cw6[w]);
        const float t0 = (wv & 2) ? sw6[0] : cw6[0];   // wire0 bit = wv>>1
        const float t1 = (wv & 1) ? sw6[1] : cw6[1];   // wire1 bit = wv&1
        const float A  = t0 * t1;
        float GH[4], GL[4];
        GH[0] = cw6[2] * cw6[3]; GH[1] = cw6[2] * sw6[3];
        GH[2] = sw6[2] * cw6[3]; GH[3] = sw6[2] * sw6[3];
#pragma unroll
        for (int a = 0; a < 4; ++a) GH[a] *= A;
        GL[0] = cw6[4] * cw6[5]; GL[1] = cw6[4] * sw6[5];
        GL[2] = sw6[4] * cw6[5]; GL[3] = sw6[4] * sw6[5];
        v2f y = {0.f, 0.f};
#pragma unroll
        for (int a = 0; a < 4; ++a) {
            v2f T = {0.f, 0.f};
#pragma unroll
            for (int b2 = 0; b2 < 4; ++b2)
                T = pkfma(GL[b2], Mres[4 * a + b2], T);
            y = pkfma(GH[a], T, y);
        }
        acc = y;
    };

    // walking pointers
    const float* cp = cl + (dir ? (SEQ - 1) * 12 : 0);
    const int   cstep = dir ? -12 : 12;
    float*       zp = zb + (dir ? (SEQ - 1) * NW : 0);
    const int   zstep = dir ? -NW : NW;

    __syncthreads();                         // staging visible

    // ---- peel: partial for t=0 (h=0) + xq preload for t=0 ----
    v2f myacc;
    encode_matvec(myacc);
    pY[0][wv][lane] = (float2){myacc.x, myacc.y};
    float4 xq0 = ((const float4*)cp)[0];
    float4 xq1 = ((const float4*)cp)[1];
    float4 xq2 = ((const float4*)cp)[2];
    cp += cstep;
    __syncthreads();                         // pY[0] visible

    for (int t = 0; t < SEQ; ++t) {
        const int buf = t & 1;

        // reassemble full y: 3 partner partials + my own
        const float2 yA = pY[buf][ow0][lane];
        const float2 yB = pY[buf][ow1][lane];
        const float2 yC = pY[buf][ow2][lane];
        const float yr = (myacc.x + yA.x) + (yB.x + yC.x);
        const float yi = (myacc.y + yA.y) + (yB.y + yC.y);
        const int yri = __float_as_int(yr), yii = __float_as_int(yi);

        // partners y[lane ^ m]: all VALU/DPP (verified r3/r4)
        float pr[6], pi[6];
        {   // xor32 via permlane32_swap
            auto r0 = __builtin_amdgcn_permlane32_swap(yri, yri, false, false);
            auto r1 = __builtin_amdgcn_permlane32_swap(yii, yii, false, false);
            pr[0] = __int_as_float((int)((lane & 32) ? r0[0] : r0[1]));
            pi[0] = __int_as_float((int)((lane & 32) ? r1[0] : r1[1]));
        }
        {   // xor16 via permlane16_swap
            auto r0 = __builtin_amdgcn_permlane16_swap(yri, yri, false, false);
            auto r1 = __builtin_amdgcn_permlane16_swap(yii, yii, false, false);
            pr[1] = __int_as_float((int)((lane & 16) ? r0[0] : r0[1]));
            pi[1] = __int_as_float((int)((lane & 16) ? r1[0] : r1[1]));
        }
        pr[2] = dpp_mov<0x128>(yr);   // row_ror:8 == xor8 within 16-row
        pi[2] = dpp_mov<0x128>(yi);
        pr[3] = dpp_mov<0x141>(dpp_mov<0x1B>(yr));  // (i^3)^7 = i^4
        pi[3] = dpp_mov<0x141>(dpp_mov<0x1B>(yi));
        pr[4] = dpp_mov<0x4E>(yr);    // quad_perm [2,3,0,1] == xor2
        pi[4] = dpp_mov<0x4E>(yi);
        pr[5] = dpp_mov<0xB1>(yr);    // quad_perm [1,0,3,2] == xor1
        pi[5] = dpp_mov<0xB1>(yi);

        const float q = fmaf(yr, yr, yi * yi);
        const float cx[6] = {xq0.x, xq0.z, xq1.x, xq1.z, xq2.x, xq2.z};
        const float sx[6] = {xq0.y, xq0.w, xq1.y, xq1.w, xq2.y, xq2.w};

        // per-lane contribution to z_w = cx*Z_w - sx*X_w (folded, verified)
        float v[6];
#pragma unroll
        for (int w = 0; w < 6; ++w) {
            const float cq  = __int_as_float(__float_as_int(cx[w] * q) ^ zmask[w]);
            const float dot = fmaf(yr, pr[w], yi * pi[w]);
            v[w] = fmaf(-sx[w], dot, cq);
        }

        // xq for step t+1 — off the post-barrier path, xq regs now dead
        if (t + 1 < SEQ) {
            xq0 = ((const float4*)cp)[0];
            xq1 = ((const float4*)cp)[1];
            xq2 = ((const float4*)cp)[2];
            cp += cstep;
        }

        red_stage6<0x111>(v);   // row_shr:1
        red_stage6<0x112>(v);   // row_shr:2
        red_stage6<0x114>(v);   // row_shr:4
        red_stage6<0x118>(v);   // row_shr:8
        red_stage6<0x142>(v);   // row_bcast:15
        red_stage6<0x143>(v);   // row_bcast:31

        if (tid == 63) {                     // one lane buffers outputs
#pragma unroll
            for (int w = 0; w < 6; ++w) zp[w] = v[w];
        }
        zp += zstep;
#pragma unroll
        for (int w = 0; w < 6; ++w)
            h[w] = __int_as_float(
                __builtin_amdgcn_readlane(__float_as_int(v[w]), 63));

        // next state's partial into the other buffer
        encode_matvec(myacc);
        pY[buf ^ 1][wv][lane] = (float2){myacc.x, myacc.y};
        __syncthreads();                     // the ONLY barrier per step
    }

    // ---- bulk store outputs: 768 float4 over 256 threads ----
    {
        const float4* zs4 = (const float4*)zb;
        float4* go = (float4*)(hbuf + (size_t)dir * NELEM +
                               (size_t)b * (SEQ * NW));
#pragma unroll
        for (int k = 0; k < 3; ++k) {
            const int idx = tid + k * 256;
            go[idx] = zs4[idx];
        }
    }
}

// ---------------------------------------------------------------------------
// Kernel 3: out = sigmoid(fc)*h_fwd + sigmoid(bc)*h_bwd, dtype per flag.
// ---------------------------------------------------------------------------
__global__ void k_combine(const float* __restrict__ hbuf,
                          const float* __restrict__ misc,
                          void* __restrict__ out, const int* __restrict__ flag) {
    const int i = blockIdx.x * blockDim.x + threadIdx.x;
    if (i >= NELEM) return;
    const float sf = 1.f / (1.f + __expf(-misc[76]));
    const float sb = 1.f / (1.f + __expf(-misc[77]));
    const float v = sf * hbuf[i] + sb * hbuf[NELEM + i];
    if (*flag) ((__hip_bfloat16*)out)[i] = __float2bfloat16(v);
    else       ((float*)out)[i] = v;
}

// ---------------------------------------------------------------------------
extern "C" void kernel_launch(void* const* d_in, const int* in_sizes, int n_in,
                              void* d_out, int out_size, void* d_ws, size_t ws_size,
                              hipStream_t stream) {
    const void* ang  = d_in[0];
    const void* poly = d_in[1];
    const void* fp   = d_in[2];
    const void* bp   = d_in[3];
    const void* fc   = d_in[4];
    const void* bc   = d_in[5];

    // ws (floats): pad[32] | misc[128] | hbuf[2*NELEM] | Mg[16384] | flag
    float* misc = (float*)d_ws + 32;
    float* hbuf = misc + 128;
    float* Mg   = hbuf + 2 * NELEM;
    int*   flag = (int*)(Mg + 2 * 64 * 64 * 2);

    k_prep<<<33, 256, 0, stream>>>(ang, poly, fp, bp, fc, bc, misc, Mg, flag);
    k_sim<<<256, 256, 0, stream>>>(ang, Mg, hbuf, flag);
    k_combine<<<(NELEM + 255) / 256, 256, 0, stream>>>(hbuf, misc, d_out, flag);
}

// Round 6
// 344.852 us; speedup vs baseline: 1.1385x; 1.1061x over previous
//
#include <hip/hip_runtime.h>
#include <hip/hip_bf16.h>
#include <stdint.h>

#define BATCH 128
#define SEQ   512
#define NW    6
#define DIM   64
#define NELEM (BATCH * SEQ * NW)   // 393216
#define PI_F  3.14159265358979323846f

typedef float v2f __attribute__((ext_vector_type(2)));
typedef uint16_t u16x8 __attribute__((ext_vector_type(8)));

__device__ __forceinline__ v2f pkfma(float s, v2f m, v2f a) {
    return __builtin_elementwise_fma((v2f){s, s}, m, a);
}

// DPP move: v[lane] = v[src(lane)] per CTRL (all source lanes valid).
template <int CTRL>
__device__ __forceinline__ float dpp_mov(float x) {
    return __int_as_float(__builtin_amdgcn_update_dpp(
        0, __float_as_int(x), CTRL, 0xF, 0xF, false));
}

// DPP add stage with bound_ctrl=true (foldable to v_add_f32_dpp, no zero-mov;
// all CTRLs used have valid sources on every lane).
template <int CTRL>
__device__ __forceinline__ float dpp_add(float v) {
    return v + __int_as_float(__builtin_amdgcn_update_dpp(
        0, __float_as_int(v), CTRL, 0xF, 0xF, true));
}

// permlane swap-add: with a=b=v, outputs hold the two halves duplicated, so
// r[0]+r[1] = pair-sum broadcast to all lanes (16: row-pairs; 32: halves).
__device__ __forceinline__ float swap16_add(float v) {
    auto r = __builtin_amdgcn_permlane16_swap(
        __float_as_int(v), __float_as_int(v), false, false);
    return __int_as_float((int)r[0]) + __int_as_float((int)r[1]);
}
__device__ __forceinline__ float swap32_add(float v) {
    auto r = __builtin_amdgcn_permlane32_swap(
        __float_as_int(v), __float_as_int(v), false, false);
    return __int_as_float((int)r[0]) + __int_as_float((int)r[1]);
}

// Branch-free sincos(h/2), |h| <= 1. Trimmed to the bf16-output tolerance.
__device__ __forceinline__ void sincos_half(float h, float& s, float& c) {
    const float u = h * h;
    c = fmaf(u, fmaf(u, 2.6041667e-3f, -0.125f), 1.0f);
    s = h * fmaf(u, fmaf(u, 2.6041667e-4f, -2.0833333e-2f), 0.5f);
}

__device__ __forceinline__ float ldf(const void* p, int i, bool bf) {
    if (bf) {
        uint32_t u = (uint32_t)((const uint16_t*)p)[i];
        return __uint_as_float(u << 16);
    }
    return ((const float*)p)[i];
}

// ---------------------------------------------------------------------------
// Kernel 1 (msetup + misc):
//  - blocks [0,32): 4 waves/block evolve one (dir,col) basis column -> Mg
//  - block 32: misc fills + flag post
// ---------------------------------------------------------------------------
__global__ void k_prep(const void* ang, const void* poly, const void* fp,
                       const void* bp, const void* fc, const void* bc,
                       float* __restrict__ misc, float* __restrict__ Mg,
                       int* __restrict__ flag) {
    __shared__ int cnt;
    if (threadIdx.x == 0) cnt = 0;
    __syncthreads();
    {
        uint32_t w = ((const uint32_t*)ang)[threadIdx.x & 255];
        uint32_t e = (w >> 8) & 0xFFu;
        if (e >= 0x3Au && e <= 0x41u) atomicAdd(&cnt, 1);
    }
    __syncthreads();
    const bool bf = (cnt >= 128);

    if (blockIdx.x == 32) {
        if (threadIdx.x == 0)      misc[76] = ldf(fc, 0, bf);
        else if (threadIdx.x == 1) misc[77] = ldf(bc, 0, bf);
        else if (threadIdx.x == 2) *flag = bf ? 1 : 0;
        return;
    }

    // ---- msetup path: 4 columns per block (one per wave) ----
    const int lane = threadIdx.x & 63;
    const int tix  = blockIdx.x * 4 + (threadIdx.x >> 6);
    const int dir  = tix >> 6;
    const int col  = tix & 63;
    const void* prm = dir ? bp : fp;
    const int p = lane;

    float yr = (p == col) ? 1.f : 0.f;
    float yi = 0.f;

#pragma unroll
    for (int d = 0; d < 4; ++d) {
        const float th = 0.5f * PI_F * ldf(poly, d, bf) *
                         (float)(6 - 2 * (int)__popc((unsigned)p));
        float s, c;
        __sincosf(th, &s, &c);
        const float nr = yr * c + yi * s;
        const float ni = yi * c - yr * s;
        yr = nr; yi = ni;
#pragma unroll
        for (int k = 0; k < 6; ++k) {
            const int cw = k, tw = (k + 1) % 6;
            const int src = p ^ (((p >> (5 - cw)) & 1) << (5 - tw));
            yr = __shfl(yr, src, 64);
            yi = __shfl(yi, src, 64);
        }
    }

    int idx = 0;
#pragma unroll
    for (int l = 0; l < 2; ++l) {
#pragma unroll
        for (int w = 0; w < 6; ++w) {
            float cx, sx, cy, sy, cz, sz;
            __sincosf(0.5f * ldf(prm, idx + 0, bf), &sx, &cx);
            __sincosf(0.5f * ldf(prm, idx + 1, bf), &sy, &cy);
            __sincosf(0.5f * ldf(prm, idx + 2, bf), &sz, &cz);
            idx += 3;
            const float A = cy * cx, B = sy * sx, C = sy * cx, D = cy * sx;
            const float U00r = cz * A + sz * B, U00i = cz * B - sz * A;
            const float U11r = U00r,            U11i = sz * A - cz * B;
            const float Xr   = cz * C + sz * D, Xi   = sz * C - cz * D;
            const int m  = 1 << (5 - w);
            const int bb = (p >> (5 - w)) & 1;
            const float C1r = bb ? U11r : U00r;
            const float C1i = bb ? U11i : U00i;
            const float C2r = bb ? Xr : -Xr;
            const float C2i = Xi;
            const float pr = __shfl_xor(yr, m, 64);
            const float pi = __shfl_xor(yi, m, 64);
            const float nr = C1r * yr - C1i * yi + C2r * pr - C2i * pi;
            const float ni = C1r * yi + C1i * yr + C2r * pi + C2i * pr;
            yr = nr; yi = ni;
        }
#pragma unroll
        for (int k = 0; k < 5; ++k) {
            const int src = p ^ (((p >> (5 - k)) & 1) << (5 - (k + 1)));
            yr = __shfl(yr, src, 64);
            yi = __shfl(yi, src, 64);
        }
    }

    float* out = Mg + ((size_t)(dir * 64 + p) * 64 + (size_t)col) * 2;
    out[0] = yr;
    out[1] = yi;
}

// ---------------------------------------------------------------------------
// Kernel 2: recurrent sim — 4 waves/chain, one barrier/step (round-5 base,
// proven VGPR-resident), with the measurement instruction diet:
//   * product-trick dots: d',s' = permlane_swap(y,y) gives d'*s' =
//     y[l]*y[l^m] on EVERY lane -> no cndmask selects at all.
//   * butterfly reduce-to-ALL: xor1,xor2 quad_perm; i^7 half_mirror (==xor4
//     on quad-uniform data); i^15 row_mirror (==xor8); then permlane16/32
//     swap-adds (r[0]+r[1] = pair-sum broadcast). Totals land on ALL lanes
//     -> the 6 readlane broadcasts are deleted; h stays in uniform VGPRs.
//   * tree adds use bound_ctrl=true (no zero-mov materialization).
// ---------------------------------------------------------------------------
__global__ void __launch_bounds__(256, 1) k_sim(const void* __restrict__ ang,
                                                const float* __restrict__ Mg,
                                                float* __restrict__ hbuf,
                                                const int* __restrict__ flag) {
    const int tid   = threadIdx.x;
    const int lane  = tid & 63;
    const int wv    = tid >> 6;              // wave 0..3
    const int chain = blockIdx.x;            // 0..255
    const int dir   = chain >> 7;
    const int b     = chain & 127;
    const bool bf   = (*flag != 0);

    __shared__ __align__(16) float  cl[SEQ * 12];   // 24 KB cos/sin(x)
    __shared__ __align__(16) float  zb[SEQ * NW];   // 12 KB output buffer
    __shared__ float2 pY[2][4][DIM];                // ping-pong partials, 4 KB

    // ---- stage: convert this chain's 3072 angles -> cos/sin in LDS ----
    if (!bf) {
        const float4* src =
            (const float4*)((const float*)ang + (size_t)b * (SEQ * NW));
#pragma unroll
        for (int k = 0; k < 3; ++k) {
            const int v = k * 256 + tid;          // float4 index 0..767
            const float4 a = src[v];
            __align__(16) float o[8];
            float s, c;
            __sincosf(a.x, &s, &c); o[0] = c; o[1] = s;
            __sincosf(a.y, &s, &c); o[2] = c; o[3] = s;
            __sincosf(a.z, &s, &c); o[4] = c; o[5] = s;
            __sincosf(a.w, &s, &c); o[6] = c; o[7] = s;
            ((float4*)cl)[2 * v]     = ((const float4*)o)[0];
            ((float4*)cl)[2 * v + 1] = ((const float4*)o)[1];
        }
    } else {
        const u16x8* src =
            (const u16x8*)((const uint16_t*)ang + (size_t)b * (SEQ * NW));
#pragma unroll
        for (int k = 0; k < 2; ++k) {
            const int v = k * 256 + tid;          // u16x8 index 0..383
            if (v < 384) {
                const u16x8 a = src[v];
                __align__(16) float o[16];
#pragma unroll
                for (int e = 0; e < 8; ++e) {
                    const float x = __uint_as_float(((uint32_t)a[e]) << 16);
                    float s, c;
                    __sincosf(x, &s, &c);
                    o[2 * e] = c; o[2 * e + 1] = s;
                }
#pragma unroll
                for (int j = 0; j < 4; ++j)
                    ((float4*)cl)[4 * v + j] = ((const float4*)o)[j];
            }
        }
    }

    // ---- my 16 resident M columns: row = lane, cols = 16wv..16wv+15 ----
    v2f Mres[16];
    {
        const float2* mr2 =
            (const float2*)(Mg + (size_t)(dir * 64 + lane) * 128 + 32 * wv);
#pragma unroll
        for (int k = 0; k < 16; ++k) Mres[k] = (v2f){mr2[k].x, mr2[k].y};
    }

    // per-wire Z sign masks
    int zmask[6];
#pragma unroll
    for (int w = 0; w < 6; ++w) zmask[w] = ((lane >> (5 - w)) & 1) << 31;
    const int ow0 = wv ^ 1, ow1 = wv ^ 2, ow2 = wv ^ 3;   // other waves

    float h[6] = {0.f, 0.f, 0.f, 0.f, 0.f, 0.f};

    // encode h -> my 16-col matvec partial (round-0 verbatim, verified)
    auto encode_matvec = [&](v2f& acc) {
        float cw6[6], sw6[6];
#pragma unroll
        for (int w = 0; w < 6; ++w) sincos_half(h[w], sw6[w], cw6[w]);
        const float t0 = (wv & 2) ? sw6[0] : cw6[0];   // wire0 bit = wv>>1
        const float t1 = (wv & 1) ? sw6[1] : cw6[1];   // wire1 bit = wv&1
        const float A  = t0 * t1;
        float GH[4], GL[4];
        GH[0] = cw6[2] * cw6[3]; GH[1] = cw6[2] * sw6[3];
        GH[2] = sw6[2] * cw6[3]; GH[3] = sw6[2] * sw6[3];
#pragma unroll
        for (int a = 0; a < 4; ++a) GH[a] *= A;
        GL[0] = cw6[4] * cw6[5]; GL[1] = cw6[4] * sw6[5];
        GL[2] = sw6[4] * cw6[5]; GL[3] = sw6[4] * sw6[5];
        v2f y = {0.f, 0.f};
#pragma unroll
        for (int a = 0; a < 4; ++a) {
            v2f T = {0.f, 0.f};
#pragma unroll
            for (int b2 = 0; b2 < 4; ++b2)
                T = pkfma(GL[b2], Mres[4 * a + b2], T);
            y = pkfma(GH[a], T, y);
        }
        acc = y;
    };

    // walking pointers
    const float* cp = cl + (dir ? (SEQ - 1) * 12 : 0);
    const int   cstep = dir ? -12 : 12;
    float*       zp = zb + (dir ? (SEQ - 1) * NW : 0);
    const int   zstep = dir ? -NW : NW;

    __syncthreads();                         // staging visible

    // ---- peel: partial for t=0 (h=0) + xq preload for t=0 ----
    v2f myacc;
    encode_matvec(myacc);
    pY[0][wv][lane] = (float2){myacc.x, myacc.y};
    float4 xq0 = ((const float4*)cp)[0];
    float4 xq1 = ((const float4*)cp)[1];
    float4 xq2 = ((const float4*)cp)[2];
    cp += cstep;
    __syncthreads();                         // pY[0] visible

    for (int t = 0; t < SEQ; ++t) {
        const int buf = t & 1;

        // reassemble full y: 3 partner partials + my own
        const float2 yA = pY[buf][ow0][lane];
        const float2 yB = pY[buf][ow1][lane];
        const float2 yC = pY[buf][ow2][lane];
        const float yr = (myacc.x + yA.x) + (yB.x + yC.x);
        const float yi = (myacc.y + yA.y) + (yB.y + yC.y);
        const int yri = __float_as_int(yr), yii = __float_as_int(yi);

        // dots y[l]·y[l^m]: product trick for swaps, DPP movs otherwise
        float dot[6];
        {   // w0: xor32 — d'*s' = y[l]*y[l^32] on every lane
            auto rr = __builtin_amdgcn_permlane32_swap(yri, yri, false, false);
            auto ri = __builtin_amdgcn_permlane32_swap(yii, yii, false, false);
            dot[0] = fmaf(__int_as_float((int)rr[0]), __int_as_float((int)rr[1]),
                          __int_as_float((int)ri[0]) * __int_as_float((int)ri[1]));
        }
        {   // w1: xor16
            auto rr = __builtin_amdgcn_permlane16_swap(yri, yri, false, false);
            auto ri = __builtin_amdgcn_permlane16_swap(yii, yii, false, false);
            dot[1] = fmaf(__int_as_float((int)rr[0]), __int_as_float((int)rr[1]),
                          __int_as_float((int)ri[0]) * __int_as_float((int)ri[1]));
        }
        dot[2] = fmaf(yr, dpp_mov<0x128>(yr), yi * dpp_mov<0x128>(yi)); // xor8
        dot[3] = fmaf(yr, dpp_mov<0x141>(dpp_mov<0x1B>(yr)),            // xor4
                      yi * dpp_mov<0x141>(dpp_mov<0x1B>(yi)));
        dot[4] = fmaf(yr, dpp_mov<0x4E>(yr), yi * dpp_mov<0x4E>(yi));   // xor2
        dot[5] = fmaf(yr, dpp_mov<0xB1>(yr), yi * dpp_mov<0xB1>(yi));   // xor1

        const float q = fmaf(yr, yr, yi * yi);
        const float cx[6] = {xq0.x, xq0.z, xq1.x, xq1.z, xq2.x, xq2.z};
        const float sx[6] = {xq0.y, xq0.w, xq1.y, xq1.w, xq2.y, xq2.w};

        // per-lane contribution to z_w = cx*Z_w - sx*X_w (folded, verified)
        float v[6];
#pragma unroll
        for (int w = 0; w < 6; ++w) {
            const float cq = __int_as_float(__float_as_int(cx[w] * q) ^ zmask[w]);
            v[w] = fmaf(-sx[w], dot[w], cq);
        }

        // xq for step t+1 — off the critical path, xq regs now dead
        if (t + 1 < SEQ) {
            xq0 = ((const float4*)cp)[0];
            xq1 = ((const float4*)cp)[1];
            xq2 = ((const float4*)cp)[2];
            cp += cstep;
        }

        // butterfly reduce-to-ALL lanes (6 values interleaved)
#pragma unroll
        for (int k = 0; k < 6; ++k) v[k] = dpp_add<0xB1>(v[k]);   // xor1
#pragma unroll
        for (int k = 0; k < 6; ++k) v[k] = dpp_add<0x4E>(v[k]);   // xor2
#pragma unroll
        for (int k = 0; k < 6; ++k) v[k] = dpp_add<0x141>(v[k]);  // ^7 ≡ xor4
#pragma unroll
        for (int k = 0; k < 6; ++k) v[k] = dpp_add<0x140>(v[k]);  // ^15 ≡ xor8
#pragma unroll
        for (int k = 0; k < 6; ++k) v[k] = swap16_add(v[k]);      // rows 16
#pragma unroll
        for (int k = 0; k < 6; ++k) v[k] = swap32_add(v[k]);      // halves

        if (tid == 63) {                     // totals on all lanes; one buffers
#pragma unroll
            for (int w = 0; w < 6; ++w) zp[w] = v[w];
        }
        zp += zstep;
#pragma unroll
        for (int w = 0; w < 6; ++w) h[w] = v[w];   // uniform VGPRs, no readlane

        // next state's partial into the other buffer
        encode_matvec(myacc);
        pY[buf ^ 1][wv][lane] = (float2){myacc.x, myacc.y};
        __syncthreads();                     // the ONLY barrier per step
    }

    // ---- bulk store outputs: 768 float4 over 256 threads ----
    {
        const float4* zs4 = (const float4*)zb;
        float4* go = (float4*)(hbuf + (size_t)dir * NELEM +
                               (size_t)b * (SEQ * NW));
#pragma unroll
        for (int k = 0; k < 3; ++k) {
            const int idx = tid + k * 256;
            go[idx] = zs4[idx];
        }
    }
}

// ---------------------------------------------------------------------------
// Kernel 3: out = sigmoid(fc)*h_fwd + sigmoid(bc)*h_bwd, dtype per flag.
// ---------------------------------------------------------------------------
__global__ void k_combine(const float* __restrict__ hbuf,
                          const float* __restrict__ misc,
                          void* __restrict__ out, const int* __restrict__ flag) {
    const int i = blockIdx.x * blockDim.x + threadIdx.x;
    if (i >= NELEM) return;
    const float sf = 1.f / (1.f + __expf(-misc[76]));
    const float sb = 1.f / (1.f + __expf(-misc[77]));
    const float v = sf * hbuf[i] + sb * hbuf[NELEM + i];
    if (*flag) ((__hip_bfloat16*)out)[i] = __float2bfloat16(v);
    else       ((float*)out)[i] = v;
}

// ---------------------------------------------------------------------------
extern "C" void kernel_launch(void* const* d_in, const int* in_sizes, int n_in,
                              void* d_out, int out_size, void* d_ws, size_t ws_size,
                              hipStream_t stream) {
    const void* ang  = d_in[0];
    const void* poly = d_in[1];
    const void* fp   = d_in[2];
    const void* bp   = d_in[3];
    const void* fc   = d_in[4];
    const void* bc   = d_in[5];

    // ws (floats): pad[32] | misc[128] | hbuf[2*NELEM] | Mg[16384] | flag
    float* misc = (float*)d_ws + 32;
    float* hbuf = misc + 128;
    float* Mg   = hbuf + 2 * NELEM;
    int*   flag = (int*)(Mg + 2 * 64 * 64 * 2);

    k_prep<<<33, 256, 0, stream>>>(ang, poly, fp, bp, fc, bc, misc, Mg, flag);
    k_sim<<<256, 256, 0, stream>>>(ang, Mg, hbuf, flag);
    k_combine<<<(NELEM + 255) / 256, 256, 0, stream>>>(hbuf, misc, d_out, flag);
}